// Round 17
// baseline (141.789 us; speedup 1.0000x reference)
//
#include <hip/hip_runtime.h>

// VQ-VAE forward: N=131072 rows (D=64), K=512 codes.
// Outputs flat: [loss(1) | quantized_st(8388608, NCHW) | perplexity(1) | encodings(131072x512)]
//
// R17: BARRIER-FREE vq_dist. R13-R16 all kept the K-split-across-waves design whose
// cross-wave argmin forces a 3-barrier chain per group (dist stuck ~60us). Inverted:
// each wave owns 32 rows and scans all 512 codes -> argmin is wave-internal, zero LDS,
// zero barriers in the hot path.
//   - X-fragments persistent in 16 VGPRs (MFMA B-operand, n=cidx k=q*8+i [R10 HW-verified]).
//   - E-fragments streamed per 16-code tile from a bf16-prepacked table in d_ws (64KB,
//     L2-resident; one dwordx4/lane per frag). A-operand m=cidx.
//   - D mapping: lane(q,cidx) holds codes tile*16+q*4+r for row cidx -> lane-local fold
//     (tile asc, r asc = k asc) + 2-step shfl_xor(16,32) with tie->lower-k.
//   - loss = Sum x^2 (at load) + Sum fd (winners); per-block partials, no atomics.
// vq_enc (quantized + encodings + counts) and vq_fin unchanged from R16.

#define OFF_Q    1
#define OFF_PERP 8388609
#define OFF_ENC  8388610

typedef float accf4 __attribute__((ext_vector_type(4)));
typedef short bfrag8 __attribute__((ext_vector_type(8)));

__device__ __forceinline__ unsigned short f2bf(float f) {
    union { float f; unsigned u; } v; v.f = f;
    unsigned r = v.u + 0x7FFFu + ((v.u >> 16) & 1u);   // RNE
    return (unsigned short)(r >> 16);
}

__device__ __forceinline__ void lds_barrier() {
    asm volatile("s_waitcnt lgkmcnt(0)" ::: "memory");
    __builtin_amdgcn_s_barrier();
    asm volatile("" ::: "memory");
}

// prep: ||e||^2, zero counts, and pack E to bf16 [code][ch] for A-fragment streaming.
__global__ __launch_bounds__(512) void vq_prep(const float* __restrict__ emb,
                                               float* __restrict__ Bk,
                                               unsigned* __restrict__ counts,
                                               unsigned* __restrict__ embB) {  // as uint2 pairs
    int k = threadIdx.x;
    const float4* e4 = reinterpret_cast<const float4*>(emb) + k * 16;
    uint2* dst = reinterpret_cast<uint2*>(embB) + k * 16;
    float s = 0.f;
    #pragma unroll
    for (int i = 0; i < 16; ++i) {
        float4 v = e4[i];
        s += v.x * v.x + v.y * v.y + v.z * v.z + v.w * v.w;
        uint2 p;
        p.x = (unsigned)f2bf(v.x) | ((unsigned)f2bf(v.y) << 16);
        p.y = (unsigned)f2bf(v.z) | ((unsigned)f2bf(v.w) << 16);
        dst[i] = p;
    }
    Bk[k] = s;
    counts[k] = 0u;
}

// ---- vq_dist: barrier-free; wave = 32 rows x all 512 codes ----
__global__ __launch_bounds__(256, 4) void vq_dist(const float* __restrict__ in,
                                                  const unsigned short* __restrict__ embB,
                                                  const float* __restrict__ Bk,
                                                  int* __restrict__ idx,
                                                  float* __restrict__ lossPart) {
    __shared__ float lossW[4];

    const int tid  = (int)threadIdx.x;
    const int lane = tid & 63;
    const int wv   = tid >> 6;          // wave 0..3
    const int q    = lane >> 4;         // quarter 0..3
    const int cidx = lane & 15;

    const int t  = (int)blockIdx.x * 4 + wv;   // task 0..4095: rows [t*32, t*32+32)
    const int bb = t >> 7;                     // batch
    const int hh = (t >> 1) & 63;              // h
    const int wh = t & 1;                      // w-half
    const size_t base = (size_t)bb * 262144 + (size_t)hh * 64 + (size_t)wh * 32;

    // X B-fragments (persistent): rt in {0,1} -> row wh*32 + rt*16 + cidx; k-ch = ks*32+q*8+i
    float lacc = 0.f;
    bfrag8 xf[2][2];
    #pragma unroll
    for (int rt = 0; rt < 2; ++rt) {
        #pragma unroll
        for (int ks = 0; ks < 2; ++ks) {
            #pragma unroll
            for (int i = 0; i < 8; ++i) {
                const float val = in[base + (size_t)(ks * 32 + q * 8 + i) * 4096 + rt * 16 + cidx];
                lacc += val * val;
                xf[rt][ks][i] = (short)f2bf(val);
            }
        }
    }

    float best0 = 3.4e38f, best1 = 3.4e38f;
    int   bk0 = q * 4,     bk1 = q * 4;

    // scan all 512 codes: 32 tiles of 16; E-frags streamed from L2-hot bf16 table
    #pragma unroll 4
    for (int tile = 0; tile < 32; ++tile) {
        const bfrag8 e0 = *reinterpret_cast<const bfrag8*>(&embB[(tile * 16 + cidx) * 64 + q * 8]);
        const bfrag8 e1 = *reinterpret_cast<const bfrag8*>(&embB[(tile * 16 + cidx) * 64 + 32 + q * 8]);
        accf4 a0 = (accf4){0.f, 0.f, 0.f, 0.f};
        accf4 a1 = (accf4){0.f, 0.f, 0.f, 0.f};
        a0 = __builtin_amdgcn_mfma_f32_16x16x32_bf16(e0, xf[0][0], a0, 0, 0, 0);
        a0 = __builtin_amdgcn_mfma_f32_16x16x32_bf16(e1, xf[0][1], a0, 0, 0, 0);
        a1 = __builtin_amdgcn_mfma_f32_16x16x32_bf16(e0, xf[1][0], a1, 0, 0, 0);
        a1 = __builtin_amdgcn_mfma_f32_16x16x32_bf16(e1, xf[1][1], a1, 0, 0, 0);

        const float4 B4 = *reinterpret_cast<const float4*>(&Bk[tile * 16 + q * 4]);
        #pragma unroll
        for (int r = 0; r < 4; ++r) {
            const float Bj = (r == 0) ? B4.x : (r == 1) ? B4.y : (r == 2) ? B4.z : B4.w;
            const int k = tile * 16 + q * 4 + r;          // tile asc, r asc => k asc per lane
            const float d0 = Bj - 2.0f * a0[r];
            if (d0 < best0) { best0 = d0; bk0 = k; }
            const float d1 = Bj - 2.0f * a1[r];
            if (d1 < best1) { best1 = d1; bk1 = k; }
        }
    }

    // reduce across the 4 q-lanes sharing cidx (xor 16, 32); tie -> lower k
    #pragma unroll
    for (int s = 16; s <= 32; s <<= 1) {
        float od = __shfl_xor(best0, s); int ok = __shfl_xor(bk0, s);
        if (od < best0 || (od == best0 && ok < bk0)) { best0 = od; bk0 = ok; }
        od = __shfl_xor(best1, s); ok = __shfl_xor(bk1, s);
        if (od < best1 || (od == best1 && ok < bk1)) { best1 = od; bk1 = ok; }
    }
    if (q == 0) {
        idx[t * 32 + cidx]      = bk0;   // row wh*32 + 0*16 + cidx
        idx[t * 32 + 16 + cidx] = bk1;   // row wh*32 + 1*16 + cidx
        lacc += best0 + best1;           // per-row loss = ||x||^2 (above) + fd
    }

    // per-block loss partial (deterministic; single end-of-kernel barrier)
    #pragma unroll
    for (int off = 32; off > 0; off >>= 1) lacc += __shfl_down(lacc, off);
    if (lane == 0) lossW[wv] = lacc;
    lds_barrier();
    if (tid == 0) {
        float s = 0.f;
        #pragma unroll
        for (int i = 0; i < 4; ++i) s += lossW[i];
        lossPart[blockIdx.x] = s;
    }
}

// ---- vq_enc: encodings (zeros + one-hot) + quantized (= emb[fk]) + counts ----
__global__ __launch_bounds__(256) void vq_enc(const int* __restrict__ idx,
                                              const float* __restrict__ emb,
                                              unsigned* __restrict__ counts,
                                              float* __restrict__ out) {
    __shared__ int ki[64];
    __shared__ float eqL[64 * 68];   // eq rows, pad 68 (16B-aligned segments)

    const int tid = (int)threadIdx.x;
    const int gab = (int)blockIdx.x;
    const int bb  = gab >> 6;
    const int hh  = gab & 63;

    if (tid < 64) ki[tid] = idx[gab * 64 + tid];
    __syncthreads();
    if (tid < 64) atomicAdd(&counts[ki[tid]], 1u);

    // stage eq rows: 4 threads per row, each 16 floats (4x float4, L2-hot emb)
    {
        const int row = tid >> 2, seg = tid & 3;
        const float4* ep = reinterpret_cast<const float4*>(emb + (size_t)ki[row] * 64 + seg * 16);
        float4* dst = reinterpret_cast<float4*>(&eqL[row * 68 + seg * 16]);
        #pragma unroll
        for (int i = 0; i < 4; ++i) dst[i] = ep[i];
    }
    __syncthreads();

    // quantized: w = tid&63, c-quarter = tid>>6; NCHW coalesced
    {
        const int w = tid & 63, cq = tid >> 6;
        const size_t qBase = OFF_Q + (size_t)bb * 262144 + (size_t)hh * 64 + (size_t)w;
        #pragma unroll
        for (int cc = 0; cc < 16; ++cc) {
            const int c = cq * 16 + cc;
            out[qBase + (size_t)c * 4096] = eqL[w * 68 + c];
        }
    }

    // encodings stream: 128KB slab, coalesced float2 (proven pattern)
    const int rh = tid >> 7;
    const int j2 = tid & 127;
    float2* enc2 = reinterpret_cast<float2*>(out + OFF_ENC + (size_t)gab * 32768);

    #pragma unroll 4
    for (int r2 = 0; r2 < 32; ++r2) {
        const int row = r2 * 2 + rh;
        const int k = ki[row];
        #pragma unroll
        for (int half = 0; half < 2; ++half) {
            const int jj = j2 + half * 128;
            float2 val;
            val.x = ((k >> 1) == jj && (k & 1) == 0) ? 1.0f : 0.0f;
            val.y = ((k >> 1) == jj && (k & 1) == 1) ? 1.0f : 0.0f;
            enc2[(size_t)row * 256 + jj] = val;
        }
    }
}

__global__ __launch_bounds__(512) void vq_fin(const unsigned* __restrict__ counts,
                                              const float* __restrict__ lossPart,
                                              float* __restrict__ out) {
    __shared__ float red[512];
    __shared__ float lr[512];
    int k = threadIdx.x;
    float p = (float)counts[k] * (1.0f / 131072.0f);   // exact: count * 2^-17
    red[k] = p * logf(p + 1e-10f);
    lr[k] = lossPart[k] + lossPart[k + 512];
    __syncthreads();
    for (int s = 256; s > 0; s >>= 1) {
        if (k < s) { red[k] += red[k + s]; lr[k] += lr[k + s]; }
        __syncthreads();
    }
    if (k == 0) {
        out[OFF_PERP] = expf(-red[0]);
        float mf = lr[0] * (1.0f / 8388608.0f);
        out[0] = mf + 0.25f * mf;   // q_latent + 0.25 * e_latent (identical values)
    }
}

extern "C" void kernel_launch(void* const* d_in, const int* in_sizes, int n_in,
                              void* d_out, int out_size, void* d_ws, size_t ws_size,
                              hipStream_t stream) {
    const float* in  = (const float*)d_in[0];
    // d_in[1] = labels (unused by the reference forward)
    const float* emb = (const float*)d_in[2];
    float* out = (float*)d_out;

    float* Bk                 = (float*)d_ws;                      // 512 f32    [0,2048)
    unsigned* counts          = (unsigned*)((char*)d_ws + 2048);   // 512 u32    [2048,4096)
    float* lossPart           = (float*)((char*)d_ws + 4096);      // 1024 f32   [4096,8192)
    unsigned* embB            = (unsigned*)((char*)d_ws + 8192);   // 64KB bf16  [8192,73728)
    int* idx                  = (int*)((char*)d_ws + 73728);       // 131072 i32 [73728,598016)

    vq_prep<<<1, 512, 0, stream>>>(emb, Bk, counts, embB);
    vq_dist<<<1024, 256, 0, stream>>>(in, (const unsigned short*)embB, Bk, idx, lossPart);
    vq_enc<<<2048, 256, 0, stream>>>(idx, emb, counts, out);
    vq_fin<<<1, 512, 0, stream>>>(counts, lossPart, out);
}

// Round 18
// 106.317 us; speedup vs baseline: 1.3336x; 1.3336x over previous
//
#include <hip/hip_runtime.h>

// VQ-VAE forward: N=131072 rows (D=64), K=512 codes.
// Outputs flat: [loss(1) | quantized_st(8388608, NCHW) | perplexity(1) | encodings(131072x512)]
//
// R18: single fused kernel with LOADS-STRICTLY-BEFORE-STORES ordering.
// R14 fusion failed because stores preceding the next group's loads force vmcnt drains
// (vmcnt counts loads AND stores). Here: phase1 = ALL x loads (4 groups -> LDS);
// phase2 = MFMA/argmin x4 (LDS-only, lgkm barriers); phase3 = ALL eq gathers (loads, regs);
// phase4 = ALL stores (idx + quantized + enc one-hot), fire-and-forget to kernel end.
// No load follows a store -> zero store-drain stalls; store streams overlap other blocks'
// compute (2 blocks/CU). Counts via separate hist kernel. Math/tie-break identical to R16.

#define OFF_Q    1
#define OFF_PERP 8388609
#define OFF_ENC  8388610

typedef float accf4 __attribute__((ext_vector_type(4)));
typedef short bfrag8 __attribute__((ext_vector_type(8)));

__device__ __forceinline__ unsigned short f2bf(float f) {
    union { float f; unsigned u; } v; v.f = f;
    unsigned r = v.u + 0x7FFFu + ((v.u >> 16) & 1u);   // RNE
    return (unsigned short)(r >> 16);
}

__device__ __forceinline__ void lds_barrier() {
    asm volatile("s_waitcnt lgkmcnt(0)" ::: "memory");
    __builtin_amdgcn_s_barrier();
    asm volatile("" ::: "memory");
}

__global__ __launch_bounds__(512) void vq_prep(const float* __restrict__ emb,
                                               float* __restrict__ Bk,
                                               unsigned* __restrict__ counts) {
    int k = threadIdx.x;
    const float4* e4 = reinterpret_cast<const float4*>(emb) + k * 16;
    float s = 0.f;
    #pragma unroll
    for (int i = 0; i < 16; ++i) {
        float4 v = e4[i];
        s += v.x * v.x + v.y * v.y + v.z * v.z + v.w * v.w;
    }
    Bk[k] = s;
    counts[k] = 0u;
}

// ---- vq_all: MFMA argmin + loss + idx + quantized + encodings, load-before-store ----
__global__ __launch_bounds__(512, 4) void vq_all(const float* __restrict__ in,
                                                 const float* __restrict__ emb,
                                                 const float* __restrict__ Bk,
                                                 int* __restrict__ idx,
                                                 float* __restrict__ lossPart,
                                                 float* __restrict__ out) {
    __shared__ __align__(16) unsigned short xB[4][64][72];  // 36864B: 4 groups staged
    __shared__ float sdw[8][64];
    __shared__ int   skw[8][64];
    __shared__ int   fkL[4][64];
    __shared__ float lossW[8];

    const int tid  = (int)threadIdx.x;
    const int lane = tid & 63;
    const int v    = __builtin_amdgcn_readfirstlane(tid >> 6);  // wave 0..7
    const int q    = lane >> 4;
    const int cidx = lane & 15;

    // E A-fragments (loads; L2-hot) — layout R10 HW-verified.
    bfrag8 efr[4][2];
    #pragma unroll
    for (int tn = 0; tn < 4; ++tn) {
        #pragma unroll
        for (int ks = 0; ks < 2; ++ks) {
            const float* ep = emb + (size_t)(v * 64 + tn * 16 + cidx) * 64 + ks * 32 + q * 8;
            float4 e0 = *reinterpret_cast<const float4*>(ep);
            float4 e1 = *reinterpret_cast<const float4*>(ep + 4);
            bfrag8 b;
            b[0] = (short)f2bf(e0.x); b[1] = (short)f2bf(e0.y);
            b[2] = (short)f2bf(e0.z); b[3] = (short)f2bf(e0.w);
            b[4] = (short)f2bf(e1.x); b[5] = (short)f2bf(e1.y);
            b[6] = (short)f2bf(e1.z); b[7] = (short)f2bf(e1.w);
            efr[tn][ks] = b;
        }
    }
    float4 Bn[4];
    #pragma unroll
    for (int tn = 0; tn < 4; ++tn)
        Bn[tn] = *reinterpret_cast<const float4*>(&Bk[v * 64 + tn * 16 + q * 4]);
    const int kbaseLane = v * 64 + q * 4;

    // ---- phase 1: load ALL 4 groups' x (32 coalesced loads/thread), pack -> LDS ----
    float lacc = 0.f;
    #pragma unroll
    for (int g = 0; g < 4; ++g) {
        const int gab = (int)blockIdx.x * 4 + g;
        const size_t rowBase = (size_t)(gab >> 6) * 262144 + (size_t)(gab & 63) * 64 + (size_t)lane;
        bfrag8 xpk;
        #pragma unroll
        for (int cc = 0; cc < 8; ++cc) {
            const float val = in[rowBase + (size_t)(v * 8 + cc) * 4096];
            lacc += val * val;
            xpk[cc] = (short)f2bf(val);
        }
        *reinterpret_cast<bfrag8*>(&xB[g][lane][v * 8]) = xpk;
    }
    lds_barrier();   // b1: all staged

    // ---- phase 2: MFMA + argmin per group (LDS-only traffic) ----
    float fdv[4]; int fkv[4];   // wave0's per-group winners (regs)
    #pragma unroll 1
    for (int g = 0; g < 4; ++g) {
        #pragma unroll
        for (int rt = 0; rt < 4; ++rt) {
            const bfrag8 x0 = *reinterpret_cast<const bfrag8*>(&xB[g][rt * 16 + cidx][q * 8]);
            const bfrag8 x1 = *reinterpret_cast<const bfrag8*>(&xB[g][rt * 16 + cidx][32 + q * 8]);
            accf4 acc[4];
            #pragma unroll
            for (int tn = 0; tn < 4; ++tn) {
                acc[tn] = (accf4){0.f, 0.f, 0.f, 0.f};
                acc[tn] = __builtin_amdgcn_mfma_f32_16x16x32_bf16(efr[tn][0], x0, acc[tn], 0, 0, 0);
                acc[tn] = __builtin_amdgcn_mfma_f32_16x16x32_bf16(efr[tn][1], x1, acc[tn], 0, 0, 0);
            }
            float best = 3.4e38f; int bk = kbaseLane;
            #pragma unroll
            for (int tn = 0; tn < 4; ++tn) {
                #pragma unroll
                for (int r = 0; r < 4; ++r) {
                    const float Bj = (r == 0) ? Bn[tn].x : (r == 1) ? Bn[tn].y : (r == 2) ? Bn[tn].z : Bn[tn].w;
                    const float d = Bj - 2.0f * acc[tn][r];
                    if (d < best) { best = d; bk = kbaseLane + tn * 16 + r; }
                }
            }
            #pragma unroll
            for (int s = 16; s <= 32; s <<= 1) {
                const float od = __shfl_xor(best, s);
                const int   ok = __shfl_xor(bk, s);
                if (od < best || (od == best && ok < bk)) { best = od; bk = ok; }
            }
            if (q == 0) {
                sdw[v][rt * 16 + cidx] = best;
                skw[v][rt * 16 + cidx] = bk;
            }
        }
        lds_barrier();   // b2_g: argmins shared

        if (v == 0) {
            float fd = sdw[0][lane];
            int   fk = skw[0][lane];
            #pragma unroll
            for (int vv = 1; vv < 8; ++vv) {
                const float dv = sdw[vv][lane];
                const int   kv = skw[vv][lane];
                if (dv < fd) { fd = dv; fk = kv; }
            }
            fkL[g][lane] = fk;
            fdv[g] = fd; fkv[g] = fk;
        }
        lds_barrier();   // b3_g: fkL visible; sdw/skw free for next group
    }

    // wave0: per-row loss = ||x||^2 (phase1) + fd
    if (v == 0) {
        #pragma unroll
        for (int g = 0; g < 4; ++g) lacc += fdv[g];
    }

    // ---- phase 3: ALL eq gathers (loads, L2-hot; still no stores issued) ----
    const int w   = tid & 63;
    const int cq8 = tid >> 6;   // channel octet 0..7
    float4 eqa[4], eqb[4];
    #pragma unroll
    for (int g = 0; g < 4; ++g) {
        const int kk = fkL[g][w];
        const float* ep = emb + (size_t)kk * 64 + cq8 * 8;
        eqa[g] = *reinterpret_cast<const float4*>(ep);
        eqb[g] = *reinterpret_cast<const float4*>(ep + 4);
    }

    // ---- phase 4: ALL stores (fire-and-forget; nothing waits on them) ----
    // idx
    if (v == 0) {
        #pragma unroll
        for (int g = 0; g < 4; ++g) idx[((int)blockIdx.x * 4 + g) * 64 + lane] = fkv[g];
    }
    // quantized: out[b, c, h, w] = emb[fk_row][c]; lanes span w -> 256B coalesced
    #pragma unroll
    for (int g = 0; g < 4; ++g) {
        const int gab = (int)blockIdx.x * 4 + g;
        const size_t qBase = OFF_Q + (size_t)(gab >> 6) * 262144 + (size_t)(gab & 63) * 64 + (size_t)w;
        #pragma unroll
        for (int cc = 0; cc < 4; ++cc)
            out[qBase + (size_t)(cq8 * 8 + cc) * 4096] = (cc == 0) ? eqa[g].x : (cc == 1) ? eqa[g].y : (cc == 2) ? eqa[g].z : eqa[g].w;
        #pragma unroll
        for (int cc = 0; cc < 4; ++cc)
            out[qBase + (size_t)(cq8 * 8 + 4 + cc) * 4096] = (cc == 0) ? eqb[g].x : (cc == 1) ? eqb[g].y : (cc == 2) ? eqb[g].z : eqb[g].w;
    }
    // encodings: per group 16384 float2, coalesced z*512+tid (proven pattern); k via ds_read
    #pragma unroll 1
    for (int g = 0; g < 4; ++g) {
        const int gab = (int)blockIdx.x * 4 + g;
        float2* enc2 = reinterpret_cast<float2*>(out + OFF_ENC + (size_t)gab * 32768);
        #pragma unroll 8
        for (int z = 0; z < 32; ++z) {
            const int p = z * 512 + tid;
            const int row = p >> 8;
            const int col2 = p & 255;
            const int k = fkL[g][row];   // LDS broadcast
            float2 val;
            val.x = ((k >> 1) == col2 && (k & 1) == 0) ? 1.0f : 0.0f;
            val.y = ((k >> 1) == col2 && (k & 1) == 1) ? 1.0f : 0.0f;
            enc2[p] = val;
        }
    }

    // loss partial (deterministic, no atomics)
    #pragma unroll
    for (int off = 32; off > 0; off >>= 1) lacc += __shfl_down(lacc, off);
    if (lane == 0) lossW[v] = lacc;
    lds_barrier();
    if (tid == 0) {
        float s = 0.f;
        #pragma unroll
        for (int i = 0; i < 8; ++i) s += lossW[i];
        lossPart[blockIdx.x] = s;
    }
}

// ---- vq_hist: counts via LDS histogram (proven R14) ----
__global__ __launch_bounds__(256) void vq_hist(const int* __restrict__ idx,
                                               unsigned* __restrict__ counts) {
    __shared__ unsigned h[512];
    const int tid = (int)threadIdx.x;
    h[tid] = 0u; h[tid + 256] = 0u;
    __syncthreads();
    const int base = (int)blockIdx.x * 2048;
    #pragma unroll
    for (int i = 0; i < 8; ++i)
        atomicAdd(&h[idx[base + i * 256 + tid]], 1u);
    __syncthreads();
    atomicAdd(&counts[tid], h[tid]);
    atomicAdd(&counts[tid + 256], h[tid + 256]);
}

__global__ __launch_bounds__(512) void vq_fin(const unsigned* __restrict__ counts,
                                              const float* __restrict__ lossPart,
                                              float* __restrict__ out) {
    __shared__ float red[512];
    __shared__ float lr[512];
    int k = threadIdx.x;
    float p = (float)counts[k] * (1.0f / 131072.0f);   // exact: count * 2^-17
    red[k] = p * logf(p + 1e-10f);
    lr[k] = lossPart[k];
    __syncthreads();
    for (int s = 256; s > 0; s >>= 1) {
        if (k < s) { red[k] += red[k + s]; lr[k] += lr[k + s]; }
        __syncthreads();
    }
    if (k == 0) {
        out[OFF_PERP] = expf(-red[0]);
        float mf = lr[0] * (1.0f / 8388608.0f);
        out[0] = mf + 0.25f * mf;   // q_latent + 0.25 * e_latent (identical values)
    }
}

extern "C" void kernel_launch(void* const* d_in, const int* in_sizes, int n_in,
                              void* d_out, int out_size, void* d_ws, size_t ws_size,
                              hipStream_t stream) {
    const float* in  = (const float*)d_in[0];
    // d_in[1] = labels (unused by the reference forward)
    const float* emb = (const float*)d_in[2];
    float* out = (float*)d_out;

    float* Bk        = (float*)d_ws;                      // 512 f32   [0,2048)
    unsigned* counts = (unsigned*)((char*)d_ws + 2048);   // 512 u32   [2048,4096)
    float* lossPart  = (float*)((char*)d_ws + 4096);      // 512 f32   [4096,6144)
    int* idx         = (int*)((char*)d_ws + 8192);        // 131072 i32

    vq_prep<<<1, 512, 0, stream>>>(emb, Bk, counts);
    vq_all<<<512, 512, 0, stream>>>(in, emb, Bk, idx, lossPart, out);
    vq_hist<<<64, 256, 0, stream>>>(idx, counts);
    vq_fin<<<1, 512, 0, stream>>>(counts, lossPart, out);
}

// Round 19
// 101.428 us; speedup vs baseline: 1.3979x; 1.0482x over previous
//
#include <hip/hip_runtime.h>

// VQ-VAE forward: N=131072 rows (D=64), K=512 codes.
// Outputs flat: [loss(1) | quantized_st(8388608, NCHW) | perplexity(1) | encodings(131072x512)]
//
// R19: R18 (loads-strictly-before-stores fused kernel, 106us) with phase 2 collapsed from
// 9 barriers to 3:
//  - all 4 groups' MFMA/argmin run back-to-back into sdw/skw[8][256] (cross-group ILP,
//    no per-group convoy), ONE barrier;
//  - every thread finalizes its own row's argmin for all 4 groups (fkv[] in regs feeds the
//    eq gather directly -- no fkL read needed there); wave0 publishes fkL for enc writes
//    behind one more barrier.
// Phase ordering (all loads before all stores), store patterns, math, tie-breaks identical
// to R18. Counts via hist kernel; loss from distances (R16 algebra).

#define OFF_Q    1
#define OFF_PERP 8388609
#define OFF_ENC  8388610

typedef float accf4 __attribute__((ext_vector_type(4)));
typedef short bfrag8 __attribute__((ext_vector_type(8)));

__device__ __forceinline__ unsigned short f2bf(float f) {
    union { float f; unsigned u; } v; v.f = f;
    unsigned r = v.u + 0x7FFFu + ((v.u >> 16) & 1u);   // RNE
    return (unsigned short)(r >> 16);
}

__device__ __forceinline__ void lds_barrier() {
    asm volatile("s_waitcnt lgkmcnt(0)" ::: "memory");
    __builtin_amdgcn_s_barrier();
    asm volatile("" ::: "memory");
}

__global__ __launch_bounds__(512) void vq_prep(const float* __restrict__ emb,
                                               float* __restrict__ Bk,
                                               unsigned* __restrict__ counts) {
    int k = threadIdx.x;
    const float4* e4 = reinterpret_cast<const float4*>(emb) + k * 16;
    float s = 0.f;
    #pragma unroll
    for (int i = 0; i < 16; ++i) {
        float4 v = e4[i];
        s += v.x * v.x + v.y * v.y + v.z * v.z + v.w * v.w;
    }
    Bk[k] = s;
    counts[k] = 0u;
}

// ---- vq_all: MFMA argmin + loss + idx + quantized + encodings; 3 barriers total ----
__global__ __launch_bounds__(512, 4) void vq_all(const float* __restrict__ in,
                                                 const float* __restrict__ emb,
                                                 const float* __restrict__ Bk,
                                                 int* __restrict__ idx,
                                                 float* __restrict__ lossPart,
                                                 float* __restrict__ out) {
    __shared__ __align__(16) unsigned short xB[4][64][72];  // 36864B: 4 groups staged
    __shared__ float sdw[8][256];                           // 8192B: [wave][g*64+row]
    __shared__ int   skw[8][256];                           // 8192B
    __shared__ int   fkL[4][64];                            // 1024B (enc writes)
    __shared__ float lossW[8];

    const int tid  = (int)threadIdx.x;
    const int lane = tid & 63;
    const int v    = __builtin_amdgcn_readfirstlane(tid >> 6);  // wave 0..7
    const int q    = lane >> 4;
    const int cidx = lane & 15;

    // E A-fragments (loads; L2-hot) — layout R10 HW-verified.
    bfrag8 efr[4][2];
    #pragma unroll
    for (int tn = 0; tn < 4; ++tn) {
        #pragma unroll
        for (int ks = 0; ks < 2; ++ks) {
            const float* ep = emb + (size_t)(v * 64 + tn * 16 + cidx) * 64 + ks * 32 + q * 8;
            float4 e0 = *reinterpret_cast<const float4*>(ep);
            float4 e1 = *reinterpret_cast<const float4*>(ep + 4);
            bfrag8 b;
            b[0] = (short)f2bf(e0.x); b[1] = (short)f2bf(e0.y);
            b[2] = (short)f2bf(e0.z); b[3] = (short)f2bf(e0.w);
            b[4] = (short)f2bf(e1.x); b[5] = (short)f2bf(e1.y);
            b[6] = (short)f2bf(e1.z); b[7] = (short)f2bf(e1.w);
            efr[tn][ks] = b;
        }
    }
    float4 Bn[4];
    #pragma unroll
    for (int tn = 0; tn < 4; ++tn)
        Bn[tn] = *reinterpret_cast<const float4*>(&Bk[v * 64 + tn * 16 + q * 4]);
    const int kbaseLane = v * 64 + q * 4;

    // ---- phase 1: load ALL 4 groups' x (32 coalesced loads/thread), pack -> LDS ----
    float lacc = 0.f;
    #pragma unroll
    for (int g = 0; g < 4; ++g) {
        const int gab = (int)blockIdx.x * 4 + g;
        const size_t rowBase = (size_t)(gab >> 6) * 262144 + (size_t)(gab & 63) * 64 + (size_t)lane;
        bfrag8 xpk;
        #pragma unroll
        for (int cc = 0; cc < 8; ++cc) {
            const float val = in[rowBase + (size_t)(v * 8 + cc) * 4096];
            lacc += val * val;
            xpk[cc] = (short)f2bf(val);
        }
        *reinterpret_cast<bfrag8*>(&xB[g][lane][v * 8]) = xpk;
    }
    lds_barrier();   // b1: all staged

    // ---- phase 2: MFMA + argmin, ALL groups back-to-back (no intermediate barriers) ----
    #pragma unroll 1
    for (int g = 0; g < 4; ++g) {
        #pragma unroll
        for (int rt = 0; rt < 4; ++rt) {
            const bfrag8 x0 = *reinterpret_cast<const bfrag8*>(&xB[g][rt * 16 + cidx][q * 8]);
            const bfrag8 x1 = *reinterpret_cast<const bfrag8*>(&xB[g][rt * 16 + cidx][32 + q * 8]);
            accf4 acc[4];
            #pragma unroll
            for (int tn = 0; tn < 4; ++tn) {
                acc[tn] = (accf4){0.f, 0.f, 0.f, 0.f};
                acc[tn] = __builtin_amdgcn_mfma_f32_16x16x32_bf16(efr[tn][0], x0, acc[tn], 0, 0, 0);
                acc[tn] = __builtin_amdgcn_mfma_f32_16x16x32_bf16(efr[tn][1], x1, acc[tn], 0, 0, 0);
            }
            float best = 3.4e38f; int bk = kbaseLane;
            #pragma unroll
            for (int tn = 0; tn < 4; ++tn) {
                #pragma unroll
                for (int r = 0; r < 4; ++r) {
                    const float Bj = (r == 0) ? Bn[tn].x : (r == 1) ? Bn[tn].y : (r == 2) ? Bn[tn].z : Bn[tn].w;
                    const float d = Bj - 2.0f * acc[tn][r];
                    if (d < best) { best = d; bk = kbaseLane + tn * 16 + r; }
                }
            }
            #pragma unroll
            for (int s = 16; s <= 32; s <<= 1) {
                const float od = __shfl_xor(best, s);
                const int   ok = __shfl_xor(bk, s);
                if (od < best || (od == best && ok < bk)) { best = od; bk = ok; }
            }
            if (q == 0) {
                sdw[v][g * 64 + rt * 16 + cidx] = best;
                skw[v][g * 64 + rt * 16 + cidx] = bk;
            }
        }
    }
    lds_barrier();   // b2: ALL groups' per-wave argmins shared

    // every thread finalizes its own row (= lane) for all 4 groups
    float fdv[4]; int fkv[4];
    #pragma unroll
    for (int g = 0; g < 4; ++g) {
        float fd = sdw[0][g * 64 + lane];
        int   fk = skw[0][g * 64 + lane];
        #pragma unroll
        for (int vv = 1; vv < 8; ++vv) {
            const float dv = sdw[vv][g * 64 + lane];
            const int   kv = skw[vv][g * 64 + lane];
            if (dv < fd) { fd = dv; fk = kv; }
        }
        fdv[g] = fd; fkv[g] = fk;
        if (v == 0) fkL[g][lane] = fk;
    }
    if (v == 0) {
        #pragma unroll
        for (int g = 0; g < 4; ++g) lacc += fdv[g];   // per-row loss = ||x||^2 + fd
    }
    lds_barrier();   // b3: fkL visible

    // ---- phase 3: ALL eq gathers (loads; own row's fk from regs; still no stores) ----
    const int w   = tid & 63;
    const int cq8 = tid >> 6;   // channel octet 0..7
    float4 eqa[4], eqb[4];
    #pragma unroll
    for (int g = 0; g < 4; ++g) {
        const float* ep = emb + (size_t)fkv[g] * 64 + cq8 * 8;
        eqa[g] = *reinterpret_cast<const float4*>(ep);
        eqb[g] = *reinterpret_cast<const float4*>(ep + 4);
    }

    // ---- phase 4: ALL stores (fire-and-forget) ----
    if (v == 0) {
        #pragma unroll
        for (int g = 0; g < 4; ++g) idx[((int)blockIdx.x * 4 + g) * 64 + lane] = fkv[g];
    }
    #pragma unroll
    for (int g = 0; g < 4; ++g) {
        const int gab = (int)blockIdx.x * 4 + g;
        const size_t qBase = OFF_Q + (size_t)(gab >> 6) * 262144 + (size_t)(gab & 63) * 64 + (size_t)w;
        #pragma unroll
        for (int cc = 0; cc < 4; ++cc)
            out[qBase + (size_t)(cq8 * 8 + cc) * 4096] = (cc == 0) ? eqa[g].x : (cc == 1) ? eqa[g].y : (cc == 2) ? eqa[g].z : eqa[g].w;
        #pragma unroll
        for (int cc = 0; cc < 4; ++cc)
            out[qBase + (size_t)(cq8 * 8 + 4 + cc) * 4096] = (cc == 0) ? eqb[g].x : (cc == 1) ? eqb[g].y : (cc == 2) ? eqb[g].z : eqb[g].w;
    }
    #pragma unroll 1
    for (int g = 0; g < 4; ++g) {
        const int gab = (int)blockIdx.x * 4 + g;
        float2* enc2 = reinterpret_cast<float2*>(out + OFF_ENC + (size_t)gab * 32768);
        #pragma unroll 8
        for (int z = 0; z < 32; ++z) {
            const int p = z * 512 + tid;
            const int row = p >> 8;
            const int col2 = p & 255;
            const int k = fkL[g][row];   // LDS broadcast
            float2 val;
            val.x = ((k >> 1) == col2 && (k & 1) == 0) ? 1.0f : 0.0f;
            val.y = ((k >> 1) == col2 && (k & 1) == 1) ? 1.0f : 0.0f;
            enc2[p] = val;
        }
    }

    // loss partial (deterministic, no atomics)
    #pragma unroll
    for (int off = 32; off > 0; off >>= 1) lacc += __shfl_down(lacc, off);
    if (lane == 0) lossW[v] = lacc;
    lds_barrier();
    if (tid == 0) {
        float s = 0.f;
        #pragma unroll
        for (int i = 0; i < 8; ++i) s += lossW[i];
        lossPart[blockIdx.x] = s;
    }
}

// ---- vq_hist: counts via LDS histogram ----
__global__ __launch_bounds__(256) void vq_hist(const int* __restrict__ idx,
                                               unsigned* __restrict__ counts) {
    __shared__ unsigned h[512];
    const int tid = (int)threadIdx.x;
    h[tid] = 0u; h[tid + 256] = 0u;
    __syncthreads();
    const int base = (int)blockIdx.x * 2048;
    #pragma unroll
    for (int i = 0; i < 8; ++i)
        atomicAdd(&h[idx[base + i * 256 + tid]], 1u);
    __syncthreads();
    atomicAdd(&counts[tid], h[tid]);
    atomicAdd(&counts[tid + 256], h[tid + 256]);
}

__global__ __launch_bounds__(512) void vq_fin(const unsigned* __restrict__ counts,
                                              const float* __restrict__ lossPart,
                                              float* __restrict__ out) {
    __shared__ float red[512];
    __shared__ float lr[512];
    int k = threadIdx.x;
    float p = (float)counts[k] * (1.0f / 131072.0f);   // exact: count * 2^-17
    red[k] = p * logf(p + 1e-10f);
    lr[k] = lossPart[k];
    __syncthreads();
    for (int s = 256; s > 0; s >>= 1) {
        if (k < s) { red[k] += red[k + s]; lr[k] += lr[k + s]; }
        __syncthreads();
    }
    if (k == 0) {
        out[OFF_PERP] = expf(-red[0]);
        float mf = lr[0] * (1.0f / 8388608.0f);
        out[0] = mf + 0.25f * mf;   // q_latent + 0.25 * e_latent (identical values)
    }
}

extern "C" void kernel_launch(void* const* d_in, const int* in_sizes, int n_in,
                              void* d_out, int out_size, void* d_ws, size_t ws_size,
                              hipStream_t stream) {
    const float* in  = (const float*)d_in[0];
    // d_in[1] = labels (unused by the reference forward)
    const float* emb = (const float*)d_in[2];
    float* out = (float*)d_out;

    float* Bk        = (float*)d_ws;                      // 512 f32   [0,2048)
    unsigned* counts = (unsigned*)((char*)d_ws + 2048);   // 512 u32   [2048,4096)
    float* lossPart  = (float*)((char*)d_ws + 4096);      // 512 f32   [4096,6144)
    int* idx         = (int*)((char*)d_ws + 8192);        // 131072 i32

    vq_prep<<<1, 512, 0, stream>>>(emb, Bk, counts);
    vq_all<<<512, 512, 0, stream>>>(in, emb, Bk, idx, lossPart, out);
    vq_hist<<<64, 256, 0, stream>>>(idx, counts);
    vq_fin<<<1, 512, 0, stream>>>(counts, lossPart, out);
}